// Round 5
// baseline (702.137 us; speedup 1.0000x reference)
//
#include <hip/hip_runtime.h>
#include <hip/hip_bf16.h>
#include <math.h>

#define Tn 1024
#define Hn 2048
#define En 64
#define Kn 6
#define In 1024
#define Gn 8
#define TGn 3
#define Cn 256
#define Sn 2048
#define RSF 2.5

typedef __bf16 bf16x8 __attribute__((ext_vector_type(8)));
typedef __bf16 bf16x4 __attribute__((ext_vector_type(4)));
typedef float f32x4 __attribute__((ext_vector_type(4)));

// swizzled byte offset within a [rows][64 bf16] (128B-row) LDS tile.
// XOR sel ((row^(row>>2))&7): uniform bank-quad spread for all our
// write patterns (stride-4 / stride-2 / consecutive rows) -> b128 floor rate.
__device__ __forceinline__ int swz(int row, int kbyte) {
  return row * 128 + (kbyte ^ ((((row >> 2) ^ row) & 7) << 4));
}

// one barrier per K-step: make LDS writes visible, never drain vmcnt.
#define BAR()                                                  \
  do {                                                         \
    asm volatile("s_waitcnt lgkmcnt(0)" ::: "memory");         \
    __builtin_amdgcn_sched_barrier(0);                         \
    __builtin_amdgcn_s_barrier();                              \
    __builtin_amdgcn_sched_barrier(0);                         \
  } while (0)

// ---------------- router: scores = sigmoid(x @ gate_w^T), fp64 accumulate ----------------
__global__ void scores_kernel(const float* __restrict__ x, const float* __restrict__ gw,
                              double* __restrict__ sc) {
  __shared__ float xs[Hn];
  int t = blockIdx.x;
  for (int i = threadIdx.x * 4; i < Hn; i += 64 * 4)
    *(float4*)(xs + i) = *(const float4*)(x + (size_t)t * Hn + i);
  __syncthreads();
  int e = threadIdx.x;
  const float* w = gw + (size_t)e * Hn;
  double a0 = 0.0, a1 = 0.0, a2 = 0.0, a3 = 0.0;
  for (int i = 0; i < Hn; i += 4) {
    float4 b = *(const float4*)(w + i);
    a0 += (double)xs[i] * b.x;
    a1 += (double)xs[i + 1] * b.y;
    a2 += (double)xs[i + 2] * b.z;
    a3 += (double)xs[i + 3] * b.w;
  }
  double acc = (a0 + a1) + (a2 + a3);
  sc[t * En + e] = 1.0 / (1.0 + exp(-acc));
}

// ---------------- grouped top-k (noaux_tc) ----------------
__global__ void topk_kernel(const double* __restrict__ sc_all, const float* __restrict__ bias,
                            int* __restrict__ ids, float* __restrict__ tw) {
  int t = blockIdx.x * blockDim.x + threadIdx.x;
  if (t >= Tn) return;
  const double* srow = sc_all + (size_t)t * En;
  double sc[En];
  for (int e = 0; e < En; ++e) sc[e] = srow[e] + (double)bias[e];
  double gsum[Gn];
  for (int g = 0; g < Gn; ++g) {
    double m1 = -1e300, m2 = -1e300;
    for (int j = 0; j < 8; ++j) {
      double v = sc[g * 8 + j];
      if (v > m1) { m2 = m1; m1 = v; } else if (v > m2) m2 = v;
    }
    gsum[g] = m1 + m2;
  }
  unsigned gsel = 0;
  for (int it = 0; it < TGn; ++it) {
    double best = -1e300; int bi = 0;
    for (int g = 0; g < Gn; ++g)
      if (!((gsel >> g) & 1) && gsum[g] > best) { best = gsum[g]; bi = g; }
    gsel |= 1u << bi;
  }
  unsigned long long taken = 0ull;
  int sel[Kn]; double w[Kn]; double wsum = 0.0;
  for (int k = 0; k < Kn; ++k) {
    double best = -1e300; int bi = 0;
    for (int e = 0; e < En; ++e) {
      if (!((gsel >> (e >> 3)) & 1)) continue;
      if ((taken >> e) & 1) continue;
      if (sc[e] > best) { best = sc[e]; bi = e; }
    }
    taken |= 1ull << bi;
    sel[k] = bi;
    w[k] = srow[bi];
    wsum += w[k];
  }
  double inv = RSF / (wsum + 1e-20);
  for (int k = 0; k < Kn; ++k) {
    ids[t * Kn + k] = sel[k];
    tw[t * Kn + k] = (float)(w[k] * inv);
  }
}

// ---------------- dispatch: parallel ballot-rank scan, cumsum position semantics ----------------
__global__ void dispatch_kernel(const int* __restrict__ ids, const float* __restrict__ tw,
                                int* __restrict__ etok, float* __restrict__ ewt,
                                int* __restrict__ ecnt) {
  int e = blockIdx.x;           // 64 blocks, one per expert
  int tid = threadIdx.x;        // 256 threads
  int lane = tid & 63, wv = tid >> 6;
  __shared__ int wcnt[4];
  int base = 0;
  for (int c = 0; c < Tn * Kn; c += 256) {
    int f = c + tid;
    bool p = (ids[f] == e);
    unsigned long long m = __ballot(p);
    int rank = __popcll(m & ((1ull << lane) - 1ull));
    if (lane == 0) wcnt[wv] = __popcll(m);
    __syncthreads();
    int woff = 0;
    for (int w = 0; w < wv; ++w) woff += wcnt[w];
    int tot = wcnt[0] + wcnt[1] + wcnt[2] + wcnt[3];
    if (p) {
      int pos = base + woff + rank;
      if (pos < Cn) { etok[e * Cn + pos] = f / Kn; ewt[e * Cn + pos] = tw[f]; }
    }
    base += tot;
    __syncthreads();
  }
  int cc = base < Cn ? base : Cn;
  for (int cpos = cc + tid; cpos < Cn; cpos += 256) {
    etok[e * Cn + cpos] = -1; ewt[e * Cn + cpos] = 0.f;
  }
  if (tid == 0) ecnt[e] = cc;
}

// ---------------- GEMM1: (gathered) x @ W13, fused SiLU*mul, bf16 out ----------------
// 256 threads, 4 waves (2m x 2n), BM=128, BN=64 out-cols (gate+up), BK=64.
// Each wave: 64 rows x (32 gate + 32 up) cols, acc 4m x 2q x {g,u}.
// Per wave per K-step: 16 ds_read_b128 : 32 MFMA.
__global__ __launch_bounds__(256, 2)
void gemm1_silu(const float* __restrict__ A, const int* __restrict__ rows,
                const int* __restrict__ ecnt, const float* __restrict__ B,
                __bf16* __restrict__ O, int Kd, int Nhalf,
                long long Bstride, long long Ostride, int swzMode) {
  int e, m0, n0;
  if (swzMode) {
    int hw = blockIdx.x;           // grid 2048: 8 xcd x 8 experts x 32 slots
    int xcd = hw & 7, slot = hw >> 3;
    e = xcd * 8 + (slot >> 5);
    int within = slot & 31;        // 2 msegs x 16 ntiles
    m0 = (within >> 4) * 128;
    n0 = (within & 15) * 64;
  } else {
    e = blockIdx.z; m0 = blockIdx.y * 128; n0 = blockIdx.x * 64;
  }
  if (ecnt && ecnt[e] <= m0) return;
  const float* Bp = B + (long long)e * Bstride;
  __bf16* Op = O + (long long)e * Ostride;

  __shared__ __attribute__((aligned(16))) __bf16 As[2][128 * 64];
  __shared__ __attribute__((aligned(16))) __bf16 Bg[2][64 * 64];
  __shared__ __attribute__((aligned(16))) __bf16 Bu[2][64 * 64];
  __shared__ int rowix[128];

  int tid = threadIdx.x;
  if (tid < 128) {
    int r;
    if (rows) { int v = rows[e * Cn + m0 + tid]; r = v < 0 ? 0 : v; }
    else r = m0 + tid;
    rowix[tid] = r;
  }
  __syncthreads();

  int lane = tid & 63;
  int wv = tid >> 6;                  // 0..3
  int wm = wv >> 1, wn = wv & 1;      // wave tile: rows wm*64, cols wn*32
  int l15 = lane & 15, lhi = lane >> 4;

  // A staging: thread -> (row tid>>1, k-half tid&1), 8 float4
  int rowA = tid >> 1, ha = tid & 1;
  const float* arow = A + (size_t)rowix[rowA] * Hn + ha * 32;

  // B staging: 128 thr gate, 128 thr up; 8 k-rows x 4 cols each
  int btid = tid & 127, half = tid >> 7;
  int kb = (btid >> 4) * 8;           // 0..56
  int cB = (btid & 15) * 4;
  size_t ldb = (size_t)2 * Nhalf;
  const float* bsrc = Bp + (size_t)kb * ldb + n0 + cB + (size_t)half * Nhalf;

  f32x4 zero = {0.f, 0.f, 0.f, 0.f};
  f32x4 accg[4][2], accu[4][2];
#pragma unroll
  for (int m = 0; m < 4; ++m)
#pragma unroll
    for (int q = 0; q < 2; ++q) { accg[m][q] = zero; accu[m][q] = zero; }

  float4 qa[8], qb[8];

#define LOADS1(K0)                                                         \
  {                                                                        \
    _Pragma("unroll") for (int i = 0; i < 8; ++i)                          \
      qa[i] = *(const float4*)(arow + (K0) + 4 * i);                       \
    _Pragma("unroll") for (int r = 0; r < 8; ++r)                          \
      qb[r] = *(const float4*)(bsrc + (size_t)((K0) + r) * ldb);           \
  }

#define WRITE1(P)                                                          \
  {                                                                        \
    _Pragma("unroll") for (int i2 = 0; i2 < 4; ++i2) {                     \
      bf16x8 h;                                                            \
      _Pragma("unroll") for (int j = 0; j < 4; ++j) {                      \
        h[j] = (__bf16)(((const float*)&qa[2 * i2])[j]);                   \
        h[4 + j] = (__bf16)(((const float*)&qa[2 * i2 + 1])[j]);           \
      }                                                                    \
      *(bf16x8*)((char*)As[P] + swz(rowA, (ha * 4 + i2) * 16)) = h;        \
    }                                                                      \
    __bf16* BtP = half ? Bu[P] : Bg[P];                                    \
    _Pragma("unroll") for (int j = 0; j < 4; ++j) {                        \
      bf16x8 cv;                                                           \
      _Pragma("unroll") for (int r = 0; r < 8; ++r)                        \
        cv[r] = (__bf16)(((const float*)&qb[r])[j]);                       \
      *(bf16x8*)((char*)BtP + swz(cB + j, kb * 2)) = cv;                   \
    }                                                                      \
  }

#define MFMA1(P)                                                           \
  _Pragma("unroll") for (int kk = 0; kk < 2; ++kk) {                       \
    int kbyte = kk * 64 + 16 * lhi;                                        \
    bf16x8 af[4];                                                          \
    _Pragma("unroll") for (int m = 0; m < 4; ++m)                          \
      af[m] = *(const bf16x8*)((char*)As[P] + swz(wm * 64 + m * 16 + l15, kbyte)); \
    _Pragma("unroll") for (int q = 0; q < 2; ++q) {                        \
      int col = wn * 32 + q * 16 + l15;                                    \
      bf16x8 fg = *(const bf16x8*)((char*)Bg[P] + swz(col, kbyte));        \
      bf16x8 fu = *(const bf16x8*)((char*)Bu[P] + swz(col, kbyte));        \
      _Pragma("unroll") for (int m = 0; m < 4; ++m) {                      \
        accg[m][q] = __builtin_amdgcn_mfma_f32_16x16x32_bf16(af[m], fg, accg[m][q], 0, 0, 0); \
        accu[m][q] = __builtin_amdgcn_mfma_f32_16x16x32_bf16(af[m], fu, accu[m][q], 0, 0, 0); \
      }                                                                    \
    }                                                                      \
  }

  int nt = Kd >> 6;
  LOADS1(0);
  WRITE1(0);
  LOADS1(64);
  BAR();
  for (int t = 0; t < nt; ++t) {
    int p = t & 1;
    __builtin_amdgcn_s_setprio(1);
    MFMA1(p);
    __builtin_amdgcn_s_setprio(0);
    if (t + 1 < nt) {
      WRITE1(p ^ 1);
      if (t + 2 < nt) LOADS1((t + 2) << 6);
    }
    BAR();
  }
#undef LOADS1
#undef WRITE1
#undef MFMA1

#pragma unroll
  for (int m = 0; m < 4; ++m)
#pragma unroll
    for (int q = 0; q < 2; ++q)
#pragma unroll
      for (int r = 0; r < 4; ++r) {
        int row = m0 + wm * 64 + m * 16 + lhi * 4 + r;
        int col = n0 + wn * 32 + q * 16 + l15;
        float g = accg[m][q][r], u = accu[m][q][r];
        float v = g / (1.f + __expf(-g)) * u;
        Op[(size_t)row * Nhalf + col] = (__bf16)v;
      }
}

// ---------------- GEMM2: mid(bf16) @ W2/shared_down, scatter-atomic or store ----------------
// 256 threads, 4 waves (2m x 2n), BM=128, BN=128, BK=64.
// Each wave: 64 rows x 64 cols, acc[4][4]. 16 ds_read_b128 : 32 MFMA.
__global__ __launch_bounds__(256, 2)
void gemm2_kernel(const __bf16* __restrict__ A, const float* __restrict__ B,
                  const int* __restrict__ etok, const float* __restrict__ ewt,
                  const int* __restrict__ ecnt, float* __restrict__ out, int Kd,
                  long long Astride, long long Bstride, int swzMode) {
  int e, m0, n0;
  if (swzMode) {
    int hw = blockIdx.x;           // grid 2048: 8 xcd x 8 experts x 32 slots
    int xcd = hw & 7, slot = hw >> 3;
    e = xcd * 8 + (slot >> 5);
    int within = slot & 31;        // 2 msegs x 16 ntiles
    m0 = (within >> 4) * 128;
    n0 = (within & 15) * 128;
  } else {
    e = blockIdx.z; m0 = blockIdx.y * 128; n0 = blockIdx.x * 128;
  }
  if (ecnt && ecnt[e] <= m0) return;
  const __bf16* Ap = A + (long long)e * Astride;
  const float* Bp = B + (long long)e * Bstride;

  __shared__ __attribute__((aligned(16))) __bf16 As[2][128 * 64];
  __shared__ __attribute__((aligned(16))) __bf16 Bs[2][128 * 64];  // [n][k]
  __shared__ int s_tok[128];
  __shared__ float s_wt[128];

  int tid = threadIdx.x;
  if (tid < 128) {
    if (etok) { s_tok[tid] = etok[e * Cn + m0 + tid]; s_wt[tid] = ewt[e * Cn + m0 + tid]; }
    else { s_tok[tid] = m0 + tid; s_wt[tid] = 1.f; }
  }
  __syncthreads();

  int lane = tid & 63;
  int wv = tid >> 6;
  int wm = wv >> 1, wn = wv & 1;
  int l15 = lane & 15, lhi = lane >> 4;

  // A staging: (row tid>>1, k-half tid&1), 4 x bf16x8
  int rowA = tid >> 1, ha = tid & 1;
  const __bf16* ap0 = Ap + (size_t)(m0 + rowA) * Kd + ha * 32;

  // B staging: 8 k-rows x 4 cols per thread over [64k][128n]
  int kb = (tid >> 5) * 8;           // 0..56
  int cB = (tid & 31) * 4;           // 0..124
  const float* bsrc = Bp + (size_t)kb * Hn + n0 + cB;

  f32x4 zero = {0.f, 0.f, 0.f, 0.f};
  f32x4 acc[4][4];
#pragma unroll
  for (int m = 0; m < 4; ++m)
#pragma unroll
    for (int q = 0; q < 4; ++q) acc[m][q] = zero;

  bf16x8 qa[4];
  float4 qb[8];

#define LOADS2(K0)                                                          \
  {                                                                         \
    _Pragma("unroll") for (int i = 0; i < 4; ++i)                           \
      qa[i] = *(const bf16x8*)(ap0 + (K0) + 8 * i);                         \
    _Pragma("unroll") for (int r = 0; r < 8; ++r)                           \
      qb[r] = *(const float4*)(bsrc + (size_t)((K0) + r) * Hn);             \
  }

#define WRITE2(P)                                                           \
  {                                                                         \
    _Pragma("unroll") for (int i = 0; i < 4; ++i)                           \
      *(bf16x8*)((char*)As[P] + swz(rowA, (ha * 4 + i) * 16)) = qa[i];      \
    _Pragma("unroll") for (int j = 0; j < 4; ++j) {                         \
      bf16x8 cv;                                                            \
      _Pragma("unroll") for (int r = 0; r < 8; ++r)                         \
        cv[r] = (__bf16)(((const float*)&qb[r])[j]);                        \
      *(bf16x8*)((char*)Bs[P] + swz(cB + j, kb * 2)) = cv;                  \
    }                                                                       \
  }

#define MFMA2(P)                                                            \
  _Pragma("unroll") for (int kk = 0; kk < 2; ++kk) {                        \
    int kbyte = kk * 64 + 16 * lhi;                                         \
    bf16x8 af[4];                                                           \
    _Pragma("unroll") for (int m = 0; m < 4; ++m)                           \
      af[m] = *(const bf16x8*)((char*)As[P] + swz(wm * 64 + m * 16 + l15, kbyte)); \
    _Pragma("unroll") for (int q = 0; q < 4; ++q) {                         \
      bf16x8 fb = *(const bf16x8*)((char*)Bs[P] + swz(wn * 64 + q * 16 + l15, kbyte)); \
      _Pragma("unroll") for (int m = 0; m < 4; ++m)                         \
        acc[m][q] = __builtin_amdgcn_mfma_f32_16x16x32_bf16(af[m], fb, acc[m][q], 0, 0, 0); \
    }                                                                       \
  }

  int nt = Kd >> 6;
  LOADS2(0);
  WRITE2(0);
  LOADS2(64);
  BAR();
  for (int t = 0; t < nt; ++t) {
    int p = t & 1;
    __builtin_amdgcn_s_setprio(1);
    MFMA2(p);
    __builtin_amdgcn_s_setprio(0);
    if (t + 1 < nt) {
      WRITE2(p ^ 1);
      if (t + 2 < nt) LOADS2((t + 2) << 6);
    }
    BAR();
  }
#undef LOADS2
#undef WRITE2
#undef MFMA2

#pragma unroll
  for (int m = 0; m < 4; ++m)
#pragma unroll
    for (int q = 0; q < 4; ++q)
#pragma unroll
      for (int r = 0; r < 4; ++r) {
        int lrow = wm * 64 + m * 16 + lhi * 4 + r;
        int col = n0 + wn * 64 + q * 16 + l15;
        float v = acc[m][q][r];
        if (etok) {
          int tok = s_tok[lrow];
          if (tok >= 0) atomicAdd(out + (size_t)tok * Hn + col, s_wt[lrow] * v);
        } else {
          out[(size_t)(m0 + lrow) * Hn + col] = v;
        }
      }
}

extern "C" void kernel_launch(void* const* d_in, const int* in_sizes, int n_in,
                              void* d_out, int out_size, void* d_ws, size_t ws_size,
                              hipStream_t stream) {
  (void)in_sizes; (void)n_in; (void)out_size; (void)ws_size;
  const float* x   = (const float*)d_in[0];
  const float* gw  = (const float*)d_in[1];
  const float* gb  = (const float*)d_in[2];
  const float* w13 = (const float*)d_in[3];
  const float* w2  = (const float*)d_in[4];
  const float* sgu = (const float*)d_in[5];
  const float* sdn = (const float*)d_in[6];
  float* out = (float*)d_out;

  char* ws = (char*)d_ws;
  size_t off = 0;
  double* scores = (double*)(ws + off); off += (size_t)Tn * En * 8;
  int* ids   = (int*)(ws + off);   off += (size_t)Tn * Kn * 4;
  float* tw  = (float*)(ws + off); off += (size_t)Tn * Kn * 4;
  int* etok  = (int*)(ws + off);   off += (size_t)En * Cn * 4;
  float* ewt = (float*)(ws + off); off += (size_t)En * Cn * 4;
  int* ecnt  = (int*)(ws + off);   off += 256;
  __bf16* hmid = (__bf16*)(ws + off); off += (size_t)En * Cn * In * 2;
  __bf16* smid = (__bf16*)(ws + off); off += (size_t)Tn * Sn * 2;

  scores_kernel<<<Tn, 64, 0, stream>>>(x, gw, scores);
  topk_kernel<<<Tn / 256, 256, 0, stream>>>(scores, gb, ids, tw);
  dispatch_kernel<<<En, 256, 0, stream>>>(ids, tw, etok, ewt, ecnt);

  // expert gate_up + SiLU*mul -> hmid  [E,C,I] bf16   (XCD-swizzled 1D grid)
  gemm1_silu<<<dim3(2048, 1, 1), 256, 0, stream>>>(
      x, etok, ecnt, w13, hmid, Hn, In, (long long)Hn * 2 * In, (long long)Cn * In, 1);
  // shared gate_up + SiLU*mul -> smid  [T,S] bf16
  gemm1_silu<<<dim3(Sn / 64, Tn / 128, 1), 256, 0, stream>>>(
      x, nullptr, nullptr, sgu, smid, Hn, Sn, 0, 0, 0);
  // shared down -> out (direct store, initializes out)
  gemm2_kernel<<<dim3(Hn / 128, Tn / 128, 1), 256, 0, stream>>>(
      smid, sdn, nullptr, nullptr, nullptr, out, Sn, 0, 0, 0);
  // expert down -> scatter atomic add into out   (XCD-swizzled 1D grid)
  gemm2_kernel<<<dim3(2048, 1, 1), 256, 0, stream>>>(
      hmid, w2, etok, ewt, ecnt, out, In, (long long)Cn * In, (long long)In * Hn, 1);
}

// Round 6
// 615.830 us; speedup vs baseline: 1.1401x; 1.1401x over previous
//
#include <hip/hip_runtime.h>
#include <hip/hip_bf16.h>
#include <math.h>

#define Tn 1024
#define Hn 2048
#define En 64
#define Kn 6
#define In 1024
#define Gn 8
#define TGn 3
#define Cn 256
#define Sn 2048
#define RSF 2.5

typedef __bf16 bf16x8 __attribute__((ext_vector_type(8)));
typedef __bf16 bf16x4 __attribute__((ext_vector_type(4)));
typedef float f32x4 __attribute__((ext_vector_type(4)));

// swizzled byte offset within a [rows][64 bf16] (128B-row) LDS tile.
__device__ __forceinline__ int swz(int row, int kbyte) {
  return row * 128 + (kbyte ^ ((((row >> 2) ^ row) & 7) << 4));
}

// one barrier per K-step: make LDS writes visible, never drain vmcnt.
#define BAR()                                                  \
  do {                                                         \
    asm volatile("s_waitcnt lgkmcnt(0)" ::: "memory");         \
    __builtin_amdgcn_sched_barrier(0);                         \
    __builtin_amdgcn_s_barrier();                              \
    __builtin_amdgcn_sched_barrier(0);                         \
  } while (0)

// ---------------- router: sigmoid(x @ gate_w^T) in fp64 + grouped top-k ----------------
__global__ void router_kernel(const float* __restrict__ x, const float* __restrict__ gw,
                              const float* __restrict__ gb, int* __restrict__ ids,
                              float* __restrict__ tw) {
  __shared__ float xs[Hn];
  __shared__ double sds[En];
  __shared__ double gs[Gn];
  int t = blockIdx.x;
  for (int i = threadIdx.x * 4; i < Hn; i += 64 * 4)
    *(float4*)(xs + i) = *(const float4*)(x + (size_t)t * Hn + i);
  __syncthreads();
  int e = threadIdx.x;
  const float* w = gw + (size_t)e * Hn;
  double a0 = 0.0, a1 = 0.0, a2 = 0.0, a3 = 0.0;
  for (int i = 0; i < Hn; i += 4) {
    float4 b = *(const float4*)(w + i);
    a0 += (double)xs[i] * b.x;
    a1 += (double)xs[i + 1] * b.y;
    a2 += (double)xs[i + 2] * b.z;
    a3 += (double)xs[i + 3] * b.w;
  }
  double acc = (a0 + a1) + (a2 + a3);
  sds[e] = 1.0 / (1.0 + exp(-acc));
  __syncthreads();
  // group top-2 sums: lane g<8 handles group g
  if (e < Gn) {
    double m1 = -1e300, m2 = -1e300;
    for (int j = 0; j < 8; ++j) {
      double v = sds[e * 8 + j] + (double)gb[e * 8 + j];
      if (v > m1) { m2 = m1; m1 = v; } else if (v > m2) m2 = v;
    }
    gs[e] = m1 + m2;
  }
  __syncthreads();
  if (e == 0) {
    unsigned gsel = 0;
    for (int it = 0; it < TGn; ++it) {
      double best = -1e300; int bi = 0;
      for (int g = 0; g < Gn; ++g)
        if (!((gsel >> g) & 1) && gs[g] > best) { best = gs[g]; bi = g; }
      gsel |= 1u << bi;
    }
    unsigned long long taken = 0ull;
    int sel[Kn]; double wv[Kn]; double wsum = 0.0;
    for (int k = 0; k < Kn; ++k) {
      double best = -1e300; int bi = 0;
      for (int ee = 0; ee < En; ++ee) {
        if (!((gsel >> (ee >> 3)) & 1)) continue;
        if ((taken >> ee) & 1) continue;
        double v = sds[ee] + (double)gb[ee];
        if (v > best) { best = v; bi = ee; }
      }
      taken |= 1ull << bi;
      sel[k] = bi;
      wv[k] = sds[bi];
      wsum += wv[k];
    }
    double inv = RSF / (wsum + 1e-20);
    for (int k = 0; k < Kn; ++k) {
      ids[t * Kn + k] = sel[k];
      tw[t * Kn + k] = (float)(wv[k] * inv);
    }
  }
}

// ---------------- dispatch: ballot-rank scan, cumsum position semantics ----------------
__global__ void dispatch_kernel(const int* __restrict__ ids, int* __restrict__ etok,
                                int* __restrict__ ppos, int* __restrict__ ecnt) {
  int e = blockIdx.x;           // 64 blocks, one per expert
  int tid = threadIdx.x;        // 256 threads
  int lane = tid & 63, wv = tid >> 6;
  __shared__ int wcnt[4];
  int base = 0;
  for (int c = 0; c < Tn * Kn; c += 256) {
    int f = c + tid;
    bool p = (ids[f] == e);
    unsigned long long m = __ballot(p);
    int rank = __popcll(m & ((1ull << lane) - 1ull));
    if (lane == 0) wcnt[wv] = __popcll(m);
    __syncthreads();
    int woff = 0;
    for (int w = 0; w < wv; ++w) woff += wcnt[w];
    int tot = wcnt[0] + wcnt[1] + wcnt[2] + wcnt[3];
    if (p) {
      int pos = base + woff + rank;
      if (pos < Cn) { etok[e * Cn + pos] = f / Kn; ppos[f] = pos; }
      else ppos[f] = -1;
    }
    base += tot;
    __syncthreads();
  }
  int cc = base < Cn ? base : Cn;
  for (int cpos = cc + tid; cpos < Cn; cpos += 256) etok[e * Cn + cpos] = -1;
  if (tid == 0) ecnt[e] = cc;
}

// ---------------- GEMM1 fused (expert + shared): x @ W13 / x @ sgu, SiLU*mul, bf16 out ----
// 512 threads (8 waves x 16-row tiles), BM=128, BN=64(g)+64(u), BK=64, dbuf pipeline.
// hw < 256: shared-expert blocks; hw >= 256: expert blocks (XCD-decomposed).
__global__ __launch_bounds__(512, 4)
void gemm1_fused(const float* __restrict__ A, const int* __restrict__ etok,
                 const int* __restrict__ ecnt, const float* __restrict__ w13,
                 const float* __restrict__ sgu, __bf16* __restrict__ hmid,
                 __bf16* __restrict__ smid) {
  int hw = blockIdx.x;
  int m0, n0, Nhalf;
  const int* rows;
  const float* Bp;
  __bf16* Op;
  if (hw < 256) {                      // shared: 8 msegs x 32 ntiles
    int idx = hw;
    m0 = (idx >> 5) * 128; n0 = (idx & 31) * 64;
    Nhalf = Sn; Bp = sgu; Op = smid; rows = nullptr;
  } else {                             // expert: 8 xcd x 8 e x (2 mseg x 16 ntile)
    int ex = hw - 256;
    int xcd = ex & 7, slot = ex >> 3;
    int e = xcd * 8 + (slot >> 5);
    int within = slot & 31;
    m0 = (within >> 4) * 128; n0 = (within & 15) * 64;
    if (ecnt[e] <= m0) return;
    Nhalf = In; Bp = w13 + (size_t)e * Hn * 2 * In;
    Op = hmid + (size_t)e * Cn * In; rows = etok + e * Cn;
  }

  __shared__ __attribute__((aligned(16))) __bf16 As[2][128 * 64];
  __shared__ __attribute__((aligned(16))) __bf16 Bg[2][64 * 64];
  __shared__ __attribute__((aligned(16))) __bf16 Bu[2][64 * 64];
  __shared__ int rowix[128];

  int tid = threadIdx.x;
  if (tid < 128) {
    int r;
    if (rows) { int v = rows[m0 + tid]; r = v < 0 ? 0 : v; }
    else r = m0 + tid;
    rowix[tid] = r;
  }
  __syncthreads();

  int lane = tid & 63;
  int wv = tid >> 6;                 // 0..7, wave owns rows [16*wv, 16*wv+16)
  int l15 = lane & 15, lhi = lane >> 4;

  int rowA = tid >> 3, kc = (tid & 7) * 8, kcB = (tid & 7) * 16;
  const float* arow0 = A + (size_t)rowix[rowA] * Hn + kc;
  const float* arow1 = A + (size_t)rowix[rowA + 64] * Hn + kc;

  int bt = tid & 255;
  int kb = (bt >> 4) * 4;
  int cB = (bt & 15) * 4;
  size_t ldb = (size_t)2 * Nhalf;
  const float* bsrc = Bp + (size_t)kb * ldb + n0 + cB + (tid >= 256 ? Nhalf : 0);

  f32x4 zero = {0.f, 0.f, 0.f, 0.f};
  f32x4 accg[4], accu[4];
#pragma unroll
  for (int j = 0; j < 4; ++j) { accg[j] = zero; accu[j] = zero; }

  float4 qa0[2], qa1[2], qb[4];

#define LOADS1(K0)                                                         \
  {                                                                        \
    qa0[0] = *(const float4*)(arow0 + (K0));                               \
    qa0[1] = *(const float4*)(arow0 + (K0) + 4);                           \
    qa1[0] = *(const float4*)(arow1 + (K0));                               \
    qa1[1] = *(const float4*)(arow1 + (K0) + 4);                           \
    _Pragma("unroll") for (int r = 0; r < 4; ++r)                          \
      qb[r] = *(const float4*)(bsrc + (size_t)((K0) + r) * ldb);           \
  }

#define WRITE1(P)                                                          \
  {                                                                        \
    bf16x8 h0, h1;                                                         \
    _Pragma("unroll") for (int j = 0; j < 4; ++j) {                        \
      h0[j] = (__bf16)(((const float*)&qa0[0])[j]);                        \
      h0[4 + j] = (__bf16)(((const float*)&qa0[1])[j]);                    \
      h1[j] = (__bf16)(((const float*)&qa1[0])[j]);                        \
      h1[4 + j] = (__bf16)(((const float*)&qa1[1])[j]);                    \
    }                                                                      \
    *(bf16x8*)((char*)As[P] + swz(rowA, kcB)) = h0;                        \
    *(bf16x8*)((char*)As[P] + swz(rowA + 64, kcB)) = h1;                   \
    __bf16* BtP = (tid >= 256) ? Bu[P] : Bg[P];                            \
    _Pragma("unroll") for (int j = 0; j < 4; ++j) {                        \
      bf16x4 cv;                                                           \
      _Pragma("unroll") for (int r = 0; r < 4; ++r)                        \
        cv[r] = (__bf16)(((const float*)&qb[r])[j]);                       \
      *(bf16x4*)((char*)BtP + swz(cB + j, kb * 2)) = cv;                   \
    }                                                                      \
  }

#define MFMA1(P)                                                           \
  _Pragma("unroll") for (int kk = 0; kk < 2; ++kk) {                       \
    int kbyte = kk * 64 + 16 * lhi;                                        \
    bf16x8 af = *(const bf16x8*)((char*)As[P] + swz(wv * 16 + l15, kbyte));\
    _Pragma("unroll") for (int n = 0; n < 4; ++n) {                        \
      bf16x8 fg = *(const bf16x8*)((char*)Bg[P] + swz(n * 16 + l15, kbyte)); \
      accg[n] = __builtin_amdgcn_mfma_f32_16x16x32_bf16(af, fg, accg[n], 0, 0, 0); \
      bf16x8 fu = *(const bf16x8*)((char*)Bu[P] + swz(n * 16 + l15, kbyte)); \
      accu[n] = __builtin_amdgcn_mfma_f32_16x16x32_bf16(af, fu, accu[n], 0, 0, 0); \
    }                                                                      \
  }

  const int nt = Hn >> 6;
  LOADS1(0);
  WRITE1(0);
  LOADS1(64);
  BAR();
  for (int t = 0; t < nt; ++t) {
    int p = t & 1;
    __builtin_amdgcn_s_setprio(1);
    MFMA1(p);
    __builtin_amdgcn_s_setprio(0);
    if (t + 1 < nt) {
      WRITE1(p ^ 1);
      if (t + 2 < nt) LOADS1((t + 2) << 6);
    }
    BAR();
  }
#undef LOADS1
#undef WRITE1
#undef MFMA1

#pragma unroll
  for (int n = 0; n < 4; ++n)
#pragma unroll
    for (int r = 0; r < 4; ++r) {
      int row = m0 + wv * 16 + lhi * 4 + r;
      int col = n0 + n * 16 + l15;
      float g = accg[n][r], u = accu[n][r];
      float v = g / (1.f + __expf(-g)) * u;
      Op[(size_t)row * Nhalf + col] = (__bf16)v;
    }
}

// ---------------- GEMM2 fused (expert + shared): plain stores, NO atomics ----------------
// 256 threads (4 waves x 32-row tiles), BM=128, BN=64, dbuf pipeline.
// hw < 256: shared (smid @ sdn -> out); hw >= 256: expert (hmid @ w2 -> y).
__global__ __launch_bounds__(256, 4)
void gemm2_fused(const __bf16* __restrict__ hmid, const __bf16* __restrict__ smid,
                 const float* __restrict__ w2, const float* __restrict__ sdn,
                 const int* __restrict__ ecnt, float* __restrict__ y,
                 float* __restrict__ out) {
  int hw = blockIdx.x;
  int m0, n0, Kd;
  const __bf16* Ap;
  const float* Bp;
  float* dst;
  if (hw < 256) {                      // shared: 8 msegs x 32 ntiles
    int idx = hw;
    m0 = (idx >> 5) * 128; n0 = (idx & 31) * 64;
    Kd = Sn; Ap = smid; Bp = sdn; dst = out;
  } else {                             // expert: 8 xcd x 8 e x (2 mseg x 32 ntile)
    int ex = hw - 256;
    int xcd = ex & 7, slot = ex >> 3;
    int e = xcd * 8 + (slot >> 6);
    int within = slot & 63;
    m0 = (within >> 5) * 128; n0 = (within & 31) * 64;
    if (ecnt[e] <= m0) return;
    Kd = In; Ap = hmid + (size_t)e * Cn * In;
    Bp = w2 + (size_t)e * In * Hn; dst = y + (size_t)e * Cn * Hn;
  }

  __shared__ __attribute__((aligned(16))) __bf16 As[2][128 * 64];
  __shared__ __attribute__((aligned(16))) __bf16 Bs[2][64 * 64];

  int tid = threadIdx.x;
  int lane = tid & 63;
  int wr = tid >> 6;
  int l15 = lane & 15, lhi = lane >> 4;

  int rowA = tid >> 3, kc8 = (tid & 7) * 8;
  const __bf16* ap0 = Ap + (size_t)(m0 + rowA) * Kd + kc8;

  int kb = (tid >> 4) * 4;
  int cB = (tid & 15) * 4;
  const float* bp0 = Bp + (size_t)kb * Hn + n0 + cB;

  f32x4 zero = {0.f, 0.f, 0.f, 0.f};
  f32x4 acc[2][4];
#pragma unroll
  for (int i = 0; i < 2; ++i)
#pragma unroll
    for (int j = 0; j < 4; ++j) acc[i][j] = zero;

  bf16x8 qa[4];
  float4 qb[4];

#define LOADS2(K0)                                                          \
  {                                                                         \
    _Pragma("unroll") for (int it = 0; it < 4; ++it)                        \
      qa[it] = *(const bf16x8*)(ap0 + (size_t)(32 * it) * Kd + (K0));       \
    _Pragma("unroll") for (int r = 0; r < 4; ++r)                           \
      qb[r] = *(const float4*)(bp0 + (size_t)((K0) + r) * Hn);              \
  }

#define WRITE2(P)                                                           \
  {                                                                         \
    _Pragma("unroll") for (int it = 0; it < 4; ++it)                        \
      *(bf16x8*)((char*)As[P] + swz(rowA + 32 * it, kc8 * 2)) = qa[it];     \
    _Pragma("unroll") for (int j = 0; j < 4; ++j) {                         \
      bf16x4 cv;                                                            \
      _Pragma("unroll") for (int r = 0; r < 4; ++r)                         \
        cv[r] = (__bf16)(((const float*)&qb[r])[j]);                        \
      *(bf16x4*)((char*)Bs[P] + swz(cB + j, kb * 2)) = cv;                  \
    }                                                                       \
  }

#define MFMA2(P)                                                            \
  _Pragma("unroll") for (int kk = 0; kk < 2; ++kk) {                        \
    int kbyte = kk * 64 + 16 * lhi;                                         \
    bf16x8 af0 = *(const bf16x8*)((char*)As[P] + swz(wr * 32 + l15, kbyte));       \
    bf16x8 af1 = *(const bf16x8*)((char*)As[P] + swz(wr * 32 + 16 + l15, kbyte));  \
    _Pragma("unroll") for (int n = 0; n < 4; ++n) {                         \
      bf16x8 bfr = *(const bf16x8*)((char*)Bs[P] + swz(n * 16 + l15, kbyte));      \
      acc[0][n] = __builtin_amdgcn_mfma_f32_16x16x32_bf16(af0, bfr, acc[0][n], 0, 0, 0); \
      acc[1][n] = __builtin_amdgcn_mfma_f32_16x16x32_bf16(af1, bfr, acc[1][n], 0, 0, 0); \
    }                                                                       \
  }

  int nt = Kd >> 6;
  LOADS2(0);
  WRITE2(0);
  LOADS2(64);
  BAR();
  for (int t = 0; t < nt; ++t) {
    int p = t & 1;
    __builtin_amdgcn_s_setprio(1);
    MFMA2(p);
    __builtin_amdgcn_s_setprio(0);
    if (t + 1 < nt) {
      WRITE2(p ^ 1);
      if (t + 2 < nt) LOADS2((t + 2) << 6);
    }
    BAR();
  }
#undef LOADS2
#undef WRITE2
#undef MFMA2

#pragma unroll
  for (int m = 0; m < 2; ++m)
#pragma unroll
    for (int n = 0; n < 4; ++n)
#pragma unroll
      for (int r = 0; r < 4; ++r) {
        int lrow = wr * 32 + m * 16 + lhi * 4 + r;
        int col = n0 + n * 16 + l15;
        dst[(size_t)(m0 + lrow) * Hn + col] = acc[m][n][r];
      }
}

// ---------------- combine: out[t] = shared_out[t] + sum_k w_k * y[e_k, pos_k] ----------------
__global__ void combine_kernel(const int* __restrict__ ids, const float* __restrict__ tw,
                               const int* __restrict__ ppos, const float* __restrict__ y,
                               float* __restrict__ out) {
  int t = blockIdx.x;
  int c0 = threadIdx.x * 8;
  float* orow = out + (size_t)t * Hn + c0;
  float4 a0 = *(const float4*)orow;
  float4 a1 = *(const float4*)(orow + 4);
#pragma unroll
  for (int k = 0; k < Kn; ++k) {
    int f = t * Kn + k;
    int p = ppos[f];
    if (p < 0) continue;
    int e = ids[f];
    float w = tw[f];
    const float* yr = y + ((size_t)e * Cn + p) * Hn + c0;
    float4 b0 = *(const float4*)yr;
    float4 b1 = *(const float4*)(yr + 4);
    a0.x += w * b0.x; a0.y += w * b0.y; a0.z += w * b0.z; a0.w += w * b0.w;
    a1.x += w * b1.x; a1.y += w * b1.y; a1.z += w * b1.z; a1.w += w * b1.w;
  }
  *(float4*)orow = a0;
  *(float4*)(orow + 4) = a1;
}

extern "C" void kernel_launch(void* const* d_in, const int* in_sizes, int n_in,
                              void* d_out, int out_size, void* d_ws, size_t ws_size,
                              hipStream_t stream) {
  (void)in_sizes; (void)n_in; (void)out_size; (void)ws_size;
  const float* x   = (const float*)d_in[0];
  const float* gw  = (const float*)d_in[1];
  const float* gb  = (const float*)d_in[2];
  const float* w13 = (const float*)d_in[3];
  const float* w2  = (const float*)d_in[4];
  const float* sgu = (const float*)d_in[5];
  const float* sdn = (const float*)d_in[6];
  float* out = (float*)d_out;

  char* ws = (char*)d_ws;
  size_t off = 0;
  int* ids   = (int*)(ws + off);   off += (size_t)Tn * Kn * 4;
  float* tw  = (float*)(ws + off); off += (size_t)Tn * Kn * 4;
  int* ppos  = (int*)(ws + off);   off += (size_t)Tn * Kn * 4;
  int* etok  = (int*)(ws + off);   off += (size_t)En * Cn * 4;
  int* ecnt  = (int*)(ws + off);   off += 256;
  __bf16* hmid = (__bf16*)(ws + off); off += (size_t)En * Cn * In * 2;
  __bf16* smid = (__bf16*)(ws + off); off += (size_t)Tn * Sn * 2;
  float* y   = (float*)(ws + off); off += (size_t)En * Cn * Hn * 4;

  router_kernel<<<Tn, 64, 0, stream>>>(x, gw, gb, ids, tw);
  dispatch_kernel<<<En, 256, 0, stream>>>(ids, etok, ppos, ecnt);

  // gemm1: 256 shared blocks + 2048 expert blocks (XCD-decomposed)
  gemm1_fused<<<dim3(256 + 2048), 512, 0, stream>>>(x, etok, ecnt, w13, sgu, hmid, smid);
  // gemm2: 256 shared blocks (-> out) + 4096 expert blocks (-> y, no atomics)
  gemm2_fused<<<dim3(256 + 4096), 256, 0, stream>>>(hmid, smid, w2, sdn, ecnt, y, out);
  // combine: weighted gather of y + shared out
  combine_kernel<<<Tn, 256, 0, stream>>>(ids, tw, ppos, y, out);
}

// Round 7
// 590.998 us; speedup vs baseline: 1.1881x; 1.0420x over previous
//
#include <hip/hip_runtime.h>
#include <hip/hip_bf16.h>
#include <math.h>

#define Tn 1024
#define Hn 2048
#define En 64
#define Kn 6
#define In 1024
#define Gn 8
#define TGn 3
#define Cn 256
#define Sn 2048
#define RSF 2.5

typedef __bf16 bf16x8 __attribute__((ext_vector_type(8)));
typedef __bf16 bf16x4 __attribute__((ext_vector_type(4)));
typedef float f32x4 __attribute__((ext_vector_type(4)));

// swizzled byte offset within a [rows][64 bf16] (128B-row) LDS tile.
__device__ __forceinline__ int swz(int row, int kbyte) {
  return row * 128 + (kbyte ^ ((((row >> 2) ^ row) & 7) << 4));
}

// one barrier per K-step: make LDS writes visible, never drain vmcnt.
#define BAR()                                                  \
  do {                                                         \
    asm volatile("s_waitcnt lgkmcnt(0)" ::: "memory");         \
    __builtin_amdgcn_sched_barrier(0);                         \
    __builtin_amdgcn_s_barrier();                              \
    __builtin_amdgcn_sched_barrier(0);                         \
  } while (0)

// ---------------- x -> bf16 pre-pass ----------------
__global__ void xcvt_kernel(const float* __restrict__ x, __bf16* __restrict__ xbf) {
  int i = (blockIdx.x * 256 + threadIdx.x) * 8;
  float4 v0 = *(const float4*)(x + i);
  float4 v1 = *(const float4*)(x + i + 4);
  bf16x8 h;
  h[0] = (__bf16)v0.x; h[1] = (__bf16)v0.y; h[2] = (__bf16)v0.z; h[3] = (__bf16)v0.w;
  h[4] = (__bf16)v1.x; h[5] = (__bf16)v1.y; h[6] = (__bf16)v1.z; h[7] = (__bf16)v1.w;
  *(bf16x8*)(xbf + i) = h;
}

// ---------------- router: sigmoid(x @ gate_w^T) in fp64 + grouped top-k ----------------
__global__ void router_kernel(const float* __restrict__ x, const float* __restrict__ gw,
                              const float* __restrict__ gb, int* __restrict__ ids,
                              float* __restrict__ tw) {
  __shared__ float xs[Hn];
  __shared__ double sds[En];
  __shared__ double gs[Gn];
  int t = blockIdx.x;
  for (int i = threadIdx.x * 4; i < Hn; i += 64 * 4)
    *(float4*)(xs + i) = *(const float4*)(x + (size_t)t * Hn + i);
  __syncthreads();
  int e = threadIdx.x;
  const float* w = gw + (size_t)e * Hn;
  double a0 = 0.0, a1 = 0.0, a2 = 0.0, a3 = 0.0;
  for (int i = 0; i < Hn; i += 4) {
    float4 b = *(const float4*)(w + i);
    a0 += (double)xs[i] * b.x;
    a1 += (double)xs[i + 1] * b.y;
    a2 += (double)xs[i + 2] * b.z;
    a3 += (double)xs[i + 3] * b.w;
  }
  double acc = (a0 + a1) + (a2 + a3);
  sds[e] = 1.0 / (1.0 + exp(-acc));
  __syncthreads();
  if (e < Gn) {
    double m1 = -1e300, m2 = -1e300;
    for (int j = 0; j < 8; ++j) {
      double v = sds[e * 8 + j] + (double)gb[e * 8 + j];
      if (v > m1) { m2 = m1; m1 = v; } else if (v > m2) m2 = v;
    }
    gs[e] = m1 + m2;
  }
  __syncthreads();
  if (e == 0) {
    unsigned gsel = 0;
    for (int it = 0; it < TGn; ++it) {
      double best = -1e300; int bi = 0;
      for (int g = 0; g < Gn; ++g)
        if (!((gsel >> g) & 1) && gs[g] > best) { best = gs[g]; bi = g; }
      gsel |= 1u << bi;
    }
    unsigned long long taken = 0ull;
    int sel[Kn]; double wv[Kn]; double wsum = 0.0;
    for (int k = 0; k < Kn; ++k) {
      double best = -1e300; int bi = 0;
      for (int ee = 0; ee < En; ++ee) {
        if (!((gsel >> (ee >> 3)) & 1)) continue;
        if ((taken >> ee) & 1) continue;
        double v = sds[ee] + (double)gb[ee];
        if (v > best) { best = v; bi = ee; }
      }
      taken |= 1ull << bi;
      sel[k] = bi;
      wv[k] = sds[bi];
      wsum += wv[k];
    }
    double inv = RSF / (wsum + 1e-20);
    for (int k = 0; k < Kn; ++k) {
      ids[t * Kn + k] = sel[k];
      tw[t * Kn + k] = (float)(wv[k] * inv);
    }
  }
}

// ---------------- dispatch: ballot-rank scan, cumsum position semantics ----------------
__global__ void dispatch_kernel(const int* __restrict__ ids, int* __restrict__ etok,
                                int* __restrict__ ppos, int* __restrict__ ecnt) {
  int e = blockIdx.x;           // 64 blocks, one per expert
  int tid = threadIdx.x;        // 256 threads
  int lane = tid & 63, wv = tid >> 6;
  __shared__ int wcnt[4];
  int base = 0;
  for (int c = 0; c < Tn * Kn; c += 256) {
    int f = c + tid;
    bool p = (ids[f] == e);
    unsigned long long m = __ballot(p);
    int rank = __popcll(m & ((1ull << lane) - 1ull));
    if (lane == 0) wcnt[wv] = __popcll(m);
    __syncthreads();
    int woff = 0;
    for (int w = 0; w < wv; ++w) woff += wcnt[w];
    int tot = wcnt[0] + wcnt[1] + wcnt[2] + wcnt[3];
    if (p) {
      int pos = base + woff + rank;
      if (pos < Cn) { etok[e * Cn + pos] = f / Kn; ppos[f] = pos; }
      else ppos[f] = -1;
    }
    base += tot;
    __syncthreads();
  }
  int cc = base < Cn ? base : Cn;
  for (int cpos = cc + tid; cpos < Cn; cpos += 256) etok[e * Cn + cpos] = -1;
  if (tid == 0) ecnt[e] = cc;
}

// ---------------- GEMM1 fused (expert + shared): xbf @ W13 / sgu, SiLU*mul, bf16 out ----
// 512 threads (8 waves x 16-row tiles), BM=128, BN=64(g)+64(u), BK=64, dbuf pipeline.
__global__ __launch_bounds__(512, 4)
void gemm1_fused(const __bf16* __restrict__ A, const int* __restrict__ etok,
                 const int* __restrict__ ecnt, const float* __restrict__ w13,
                 const float* __restrict__ sgu, __bf16* __restrict__ hmid,
                 __bf16* __restrict__ smid) {
  int hw = blockIdx.x;
  int m0, n0, Nhalf;
  const int* rows;
  const float* Bp;
  __bf16* Op;
  if (hw < 256) {                      // shared: 8 msegs x 32 ntiles
    int idx = hw;
    m0 = (idx >> 5) * 128; n0 = (idx & 31) * 64;
    Nhalf = Sn; Bp = sgu; Op = smid; rows = nullptr;
  } else {                             // expert: 8 xcd x 8 e x (2 mseg x 16 ntile)
    int ex = hw - 256;
    int xcd = ex & 7, slot = ex >> 3;
    int e = xcd * 8 + (slot >> 5);
    int within = slot & 31;
    m0 = (within >> 4) * 128; n0 = (within & 15) * 64;
    if (ecnt[e] <= m0) return;
    Nhalf = In; Bp = w13 + (size_t)e * Hn * 2 * In;
    Op = hmid + (size_t)e * Cn * In; rows = etok + e * Cn;
  }

  __shared__ __attribute__((aligned(16))) __bf16 As[2][128 * 64];
  __shared__ __attribute__((aligned(16))) __bf16 Bg[2][64 * 64];
  __shared__ __attribute__((aligned(16))) __bf16 Bu[2][64 * 64];
  __shared__ int rowix[128];

  int tid = threadIdx.x;
  if (tid < 128) {
    int r;
    if (rows) { int v = rows[m0 + tid]; r = v < 0 ? 0 : v; }
    else r = m0 + tid;
    rowix[tid] = r;
  }
  __syncthreads();

  int lane = tid & 63;
  int wv = tid >> 6;                 // 0..7, wave owns rows [16*wv, 16*wv+16)
  int l15 = lane & 15, lhi = lane >> 4;

  int rowA = tid >> 3, kc8 = (tid & 7) * 8, kcB = (tid & 7) * 16;
  const __bf16* arow0 = A + (size_t)rowix[rowA] * Hn + kc8;
  const __bf16* arow1 = A + (size_t)rowix[rowA + 64] * Hn + kc8;

  int bt = tid & 255;
  int kb = (bt >> 4) * 4;
  int cB = (bt & 15) * 4;
  size_t ldb = (size_t)2 * Nhalf;
  const float* bsrc = Bp + (size_t)kb * ldb + n0 + cB + (tid >= 256 ? Nhalf : 0);

  f32x4 zero = {0.f, 0.f, 0.f, 0.f};
  f32x4 accg[4], accu[4];
#pragma unroll
  for (int j = 0; j < 4; ++j) { accg[j] = zero; accu[j] = zero; }

  bf16x8 qa0, qa1;
  float4 qb[4];

#define LOADS1(K0)                                                         \
  {                                                                        \
    qa0 = *(const bf16x8*)(arow0 + (K0));                                  \
    qa1 = *(const bf16x8*)(arow1 + (K0));                                  \
    _Pragma("unroll") for (int r = 0; r < 4; ++r)                          \
      qb[r] = *(const float4*)(bsrc + (size_t)((K0) + r) * ldb);           \
  }

#define WRITE1(P)                                                          \
  {                                                                        \
    *(bf16x8*)((char*)As[P] + swz(rowA, kcB)) = qa0;                       \
    *(bf16x8*)((char*)As[P] + swz(rowA + 64, kcB)) = qa1;                  \
    __bf16* BtP = (tid >= 256) ? Bu[P] : Bg[P];                            \
    _Pragma("unroll") for (int j = 0; j < 4; ++j) {                        \
      bf16x4 cv;                                                           \
      _Pragma("unroll") for (int r = 0; r < 4; ++r)                        \
        cv[r] = (__bf16)(((const float*)&qb[r])[j]);                       \
      *(bf16x4*)((char*)BtP + swz(cB + j, kb * 2)) = cv;                   \
    }                                                                      \
  }

#define MFMA1(P)                                                           \
  _Pragma("unroll") for (int kk = 0; kk < 2; ++kk) {                       \
    int kbyte = kk * 64 + 16 * lhi;                                        \
    bf16x8 af = *(const bf16x8*)((char*)As[P] + swz(wv * 16 + l15, kbyte));\
    _Pragma("unroll") for (int n = 0; n < 4; ++n) {                        \
      bf16x8 fg = *(const bf16x8*)((char*)Bg[P] + swz(n * 16 + l15, kbyte)); \
      accg[n] = __builtin_amdgcn_mfma_f32_16x16x32_bf16(af, fg, accg[n], 0, 0, 0); \
      bf16x8 fu = *(const bf16x8*)((char*)Bu[P] + swz(n * 16 + l15, kbyte)); \
      accu[n] = __builtin_amdgcn_mfma_f32_16x16x32_bf16(af, fu, accu[n], 0, 0, 0); \
    }                                                                      \
  }

  const int nt = Hn >> 6;
  LOADS1(0);
  WRITE1(0);
  LOADS1(64);
  BAR();
  for (int t = 0; t < nt; ++t) {
    int p = t & 1;
    __builtin_amdgcn_s_setprio(1);
    MFMA1(p);
    __builtin_amdgcn_s_setprio(0);
    if (t + 1 < nt) {
      WRITE1(p ^ 1);
      if (t + 2 < nt) LOADS1((t + 2) << 6);
    }
    BAR();
  }
#undef LOADS1
#undef WRITE1
#undef MFMA1

#pragma unroll
  for (int n = 0; n < 4; ++n)
#pragma unroll
    for (int r = 0; r < 4; ++r) {
      int row = m0 + wv * 16 + lhi * 4 + r;
      int col = n0 + n * 16 + l15;
      float g = accg[n][r], u = accu[n][r];
      float v = g / (1.f + __expf(-g)) * u;
      Op[(size_t)row * Nhalf + col] = (__bf16)v;
    }
}

// ---------------- GEMM2 fused (expert + shared): plain stores, NO atomics ----------------
// 256 threads (4 waves x 32-row tiles), BM=128, BN=64, dbuf pipeline.
// hw < 256: shared (smid @ sdn -> out, fp32); hw >= 256: expert (hmid @ w2 -> y, bf16).
__global__ __launch_bounds__(256, 4)
void gemm2_fused(const __bf16* __restrict__ hmid, const __bf16* __restrict__ smid,
                 const float* __restrict__ w2, const float* __restrict__ sdn,
                 const int* __restrict__ ecnt, __bf16* __restrict__ y,
                 float* __restrict__ out) {
  int hw = blockIdx.x;
  int m0, n0, Kd;
  const __bf16* Ap;
  const float* Bp;
  float* dstF = nullptr;
  __bf16* dstB = nullptr;
  if (hw < 256) {                      // shared: 8 msegs x 32 ntiles
    int idx = hw;
    m0 = (idx >> 5) * 128; n0 = (idx & 31) * 64;
    Kd = Sn; Ap = smid; Bp = sdn; dstF = out;
  } else {                             // expert: 8 xcd x 8 e x (2 mseg x 32 ntile)
    int ex = hw - 256;
    int xcd = ex & 7, slot = ex >> 3;
    int e = xcd * 8 + (slot >> 6);
    int within = slot & 63;
    m0 = (within >> 5) * 128; n0 = (within & 31) * 64;
    if (ecnt[e] <= m0) return;
    Kd = In; Ap = hmid + (size_t)e * Cn * In;
    Bp = w2 + (size_t)e * In * Hn; dstB = y + (size_t)e * Cn * Hn;
  }

  __shared__ __attribute__((aligned(16))) __bf16 As[2][128 * 64];
  __shared__ __attribute__((aligned(16))) __bf16 Bs[2][64 * 64];

  int tid = threadIdx.x;
  int lane = tid & 63;
  int wr = tid >> 6;
  int l15 = lane & 15, lhi = lane >> 4;

  int rowA = tid >> 3, kc8 = (tid & 7) * 8;
  const __bf16* ap0 = Ap + (size_t)(m0 + rowA) * Kd + kc8;

  int kb = (tid >> 4) * 4;
  int cB = (tid & 15) * 4;
  const float* bp0 = Bp + (size_t)kb * Hn + n0 + cB;

  f32x4 zero = {0.f, 0.f, 0.f, 0.f};
  f32x4 acc[2][4];
#pragma unroll
  for (int i = 0; i < 2; ++i)
#pragma unroll
    for (int j = 0; j < 4; ++j) acc[i][j] = zero;

  bf16x8 qa[4];
  float4 qb[4];

#define LOADS2(K0)                                                          \
  {                                                                         \
    _Pragma("unroll") for (int it = 0; it < 4; ++it)                        \
      qa[it] = *(const bf16x8*)(ap0 + (size_t)(32 * it) * Kd + (K0));       \
    _Pragma("unroll") for (int r = 0; r < 4; ++r)                           \
      qb[r] = *(const float4*)(bp0 + (size_t)((K0) + r) * Hn);              \
  }

#define WRITE2(P)                                                           \
  {                                                                         \
    _Pragma("unroll") for (int it = 0; it < 4; ++it)                        \
      *(bf16x8*)((char*)As[P] + swz(rowA + 32 * it, kc8 * 2)) = qa[it];     \
    _Pragma("unroll") for (int j = 0; j < 4; ++j) {                         \
      bf16x4 cv;                                                            \
      _Pragma("unroll") for (int r = 0; r < 4; ++r)                         \
        cv[r] = (__bf16)(((const float*)&qb[r])[j]);                        \
      *(bf16x4*)((char*)Bs[P] + swz(cB + j, kb * 2)) = cv;                  \
    }                                                                       \
  }

#define MFMA2(P)                                                            \
  _Pragma("unroll") for (int kk = 0; kk < 2; ++kk) {                        \
    int kbyte = kk * 64 + 16 * lhi;                                         \
    bf16x8 af0 = *(const bf16x8*)((char*)As[P] + swz(wr * 32 + l15, kbyte));       \
    bf16x8 af1 = *(const bf16x8*)((char*)As[P] + swz(wr * 32 + 16 + l15, kbyte));  \
    _Pragma("unroll") for (int n = 0; n < 4; ++n) {                         \
      bf16x8 bfr = *(const bf16x8*)((char*)Bs[P] + swz(n * 16 + l15, kbyte));      \
      acc[0][n] = __builtin_amdgcn_mfma_f32_16x16x32_bf16(af0, bfr, acc[0][n], 0, 0, 0); \
      acc[1][n] = __builtin_amdgcn_mfma_f32_16x16x32_bf16(af1, bfr, acc[1][n], 0, 0, 0); \
    }                                                                       \
  }

  int nt = Kd >> 6;
  LOADS2(0);
  WRITE2(0);
  LOADS2(64);
  BAR();
  for (int t = 0; t < nt; ++t) {
    int p = t & 1;
    __builtin_amdgcn_s_setprio(1);
    MFMA2(p);
    __builtin_amdgcn_s_setprio(0);
    if (t + 1 < nt) {
      WRITE2(p ^ 1);
      if (t + 2 < nt) LOADS2((t + 2) << 6);
    }
    BAR();
  }
#undef LOADS2
#undef WRITE2
#undef MFMA2

  if (dstF) {
#pragma unroll
    for (int m = 0; m < 2; ++m)
#pragma unroll
      for (int n = 0; n < 4; ++n)
#pragma unroll
        for (int r = 0; r < 4; ++r) {
          int lrow = wr * 32 + m * 16 + lhi * 4 + r;
          int col = n0 + n * 16 + l15;
          dstF[(size_t)(m0 + lrow) * Hn + col] = acc[m][n][r];
        }
  } else {
#pragma unroll
    for (int m = 0; m < 2; ++m)
#pragma unroll
      for (int n = 0; n < 4; ++n)
#pragma unroll
        for (int r = 0; r < 4; ++r) {
          int lrow = wr * 32 + m * 16 + lhi * 4 + r;
          int col = n0 + n * 16 + l15;
          dstB[(size_t)(m0 + lrow) * Hn + col] = (__bf16)acc[m][n][r];
        }
  }
}

// ---------------- combine: out[t] = shared_out[t] + sum_k w_k * y[e_k, pos_k] ----------------
__global__ void combine_kernel(const int* __restrict__ ids, const float* __restrict__ tw,
                               const int* __restrict__ ppos, const __bf16* __restrict__ y,
                               float* __restrict__ out) {
  int t = blockIdx.x;
  int c0 = threadIdx.x * 8;
  float* orow = out + (size_t)t * Hn + c0;
  float4 a0 = *(const float4*)orow;
  float4 a1 = *(const float4*)(orow + 4);
#pragma unroll
  for (int k = 0; k < Kn; ++k) {
    int f = t * Kn + k;
    int p = ppos[f];
    if (p < 0) continue;
    int e = ids[f];
    float w = tw[f];
    bf16x8 bv = *(const bf16x8*)(y + ((size_t)e * Cn + p) * Hn + c0);
    a0.x += w * (float)bv[0]; a0.y += w * (float)bv[1];
    a0.z += w * (float)bv[2]; a0.w += w * (float)bv[3];
    a1.x += w * (float)bv[4]; a1.y += w * (float)bv[5];
    a1.z += w * (float)bv[6]; a1.w += w * (float)bv[7];
  }
  *(float4*)orow = a0;
  *(float4*)(orow + 4) = a1;
}

extern "C" void kernel_launch(void* const* d_in, const int* in_sizes, int n_in,
                              void* d_out, int out_size, void* d_ws, size_t ws_size,
                              hipStream_t stream) {
  (void)in_sizes; (void)n_in; (void)out_size; (void)ws_size;
  const float* x   = (const float*)d_in[0];
  const float* gw  = (const float*)d_in[1];
  const float* gb  = (const float*)d_in[2];
  const float* w13 = (const float*)d_in[3];
  const float* w2  = (const float*)d_in[4];
  const float* sgu = (const float*)d_in[5];
  const float* sdn = (const float*)d_in[6];
  float* out = (float*)d_out;

  char* ws = (char*)d_ws;
  size_t off = 0;
  int* ids   = (int*)(ws + off);   off += (size_t)Tn * Kn * 4;
  float* tw  = (float*)(ws + off); off += (size_t)Tn * Kn * 4;
  int* ppos  = (int*)(ws + off);   off += (size_t)Tn * Kn * 4;
  int* etok  = (int*)(ws + off);   off += (size_t)En * Cn * 4;
  int* ecnt  = (int*)(ws + off);   off += 256;
  __bf16* xbf  = (__bf16*)(ws + off); off += (size_t)Tn * Hn * 2;
  __bf16* hmid = (__bf16*)(ws + off); off += (size_t)En * Cn * In * 2;
  __bf16* smid = (__bf16*)(ws + off); off += (size_t)Tn * Sn * 2;
  __bf16* y    = (__bf16*)(ws + off); off += (size_t)En * Cn * Hn * 2;

  xcvt_kernel<<<Tn * Hn / (256 * 8), 256, 0, stream>>>(x, xbf);
  router_kernel<<<Tn, 64, 0, stream>>>(x, gw, gb, ids, tw);
  dispatch_kernel<<<En, 256, 0, stream>>>(ids, etok, ppos, ecnt);

  // gemm1: 256 shared blocks + 2048 expert blocks (XCD-decomposed)
  gemm1_fused<<<dim3(256 + 2048), 512, 0, stream>>>(xbf, etok, ecnt, w13, sgu, hmid, smid);
  // gemm2: 256 shared blocks (-> out fp32) + 4096 expert blocks (-> y bf16)
  gemm2_fused<<<dim3(256 + 4096), 256, 0, stream>>>(hmid, smid, w2, sdn, ecnt, y, out);
  // combine: weighted gather of y + shared out
  combine_kernel<<<Tn, 256, 0, stream>>>(ids, tw, ppos, y, out);
}